// Round 1
// baseline (657.889 us; speedup 1.0000x reference)
//
#include <hip/hip_runtime.h>

#define BATCH 8
#define SLEN  2048
#define DDIM  512

typedef _Float16 f16;
typedef _Float16 half8  __attribute__((ext_vector_type(8)));
typedef _Float16 half4v __attribute__((ext_vector_type(4)));
typedef float    floatx4 __attribute__((ext_vector_type(4)));

// ---------------- pre-pass: K -> fp16 [B][S][D], V -> fp16 transposed [B][D][S] ----------------
__global__ __launch_bounds__(256) void prep_kernel(
    const float* __restrict__ Kin, const float* __restrict__ Vin,
    f16* __restrict__ Khg, f16* __restrict__ Vtg)
{
  __shared__ f16 tile[64][68];   // transpose staging (pad 68 -> stride 17 dwords, conflict-light)
  const int tid = threadIdx.x;
  const int bid = blockIdx.x;
  if (bid < 8192) {
    // K convert: 8192 blocks * 256 threads * 1 float4 = 2M float4 = 8.39M elems
    const int i4 = bid * 256 + tid;
    float4 v = ((const float4*)Kin)[i4];
    half4v h;
    h.x = (f16)v.x; h.y = (f16)v.y; h.z = (f16)v.z; h.w = (f16)v.w;
    *(half4v*)(Khg + (size_t)i4 * 4) = h;
  } else {
    // V transpose+convert: 2048 blocks = 8 batches * 32 s-tiles * 8 d-tiles (64x64 tiles)
    const int vb  = bid - 8192;
    const int b   = vb >> 8;
    const int rem = vb & 255;
    const int s0  = (rem >> 3) * 64;
    const int d0  = (rem & 7) * 64;
    const float* Vb = Vin + (size_t)b * SLEN * DDIM;
#pragma unroll
    for (int i = 0; i < 4; ++i) {
      const int eid = tid + i * 256;       // 0..1023
      const int r   = eid >> 4;            // s row 0..63
      const int c4  = (eid & 15) * 4;      // d col
      float4 f = *(const float4*)(Vb + (size_t)(s0 + r) * DDIM + d0 + c4);
      tile[c4 + 0][r] = (f16)f.x;
      tile[c4 + 1][r] = (f16)f.y;
      tile[c4 + 2][r] = (f16)f.z;
      tile[c4 + 3][r] = (f16)f.w;
    }
    __syncthreads();
    f16* VtB = Vtg + (size_t)b * DDIM * SLEN;
#pragma unroll
    for (int i = 0; i < 4; ++i) {
      const int eid = tid + i * 256;
      const int rd  = eid >> 4;            // d row 0..63
      const int c4  = (eid & 15) * 4;      // s seg
      half4v h;
      h.x = tile[rd][c4 + 0];
      h.y = tile[rd][c4 + 1];
      h.z = tile[rd][c4 + 2];
      h.w = tile[rd][c4 + 3];
      *(half4v*)(VtB + (size_t)(d0 + rd) * SLEN + s0 + c4) = h;
    }
  }
}

// ---------------- flash attention main kernel ----------------
// grid (S/64, B), block 256 = 4 waves; wave w owns q-rows [blockIdx.x*64 + w*16, +16)
// Q frags + O acc in registers; K/V 32-key tiles double-buffered in LDS; online softmax.
__global__ __launch_bounds__(256, 1) void attn_kernel(
    const float* __restrict__ Q, const f16* __restrict__ Khg,
    const f16* __restrict__ Vtg, float* __restrict__ Out)
{
  // LDS: 66,560 + 81,920 + 5,120 = 153,600 B (gfx950 group segment max 160 KiB -> 1 block/CU)
  __shared__ f16 Kh_l[2][32][520];   // [buf][key][d]  row stride 1040B = 16B-mult, +4 banks/row
  __shared__ f16 Vt_l[2][512][40];   // [buf][d][key]  row stride 80B  = 16B-mult, ~2-way banks
  __shared__ f16 P_l[4][16][40];     // per-wave P tile, C-layout -> A-layout round trip

  const int tid  = threadIdx.x;
  const int lane = tid & 63;
  const int wave = tid >> 6;
  const int col  = lane & 15;        // MFMA n/m low index
  const int quad = lane >> 4;
  const int b    = blockIdx.y;
  const int q0   = blockIdx.x * 64 + wave * 16;

  const f16* KhB = Khg + (size_t)b * SLEN * DDIM;
  const f16* VtB = Vtg + (size_t)b * DDIM * SLEN;

  // Q A-fragments in registers: A[m=lane&15][k=quad*8+j], k = d = dc*32 + quad*8 + j
  half8 qf[16];
  {
    const float* Qr = Q + (size_t)(b * SLEN + q0 + col) * DDIM + quad * 8;
#pragma unroll
    for (int dc = 0; dc < 16; ++dc) {
      float4 f0 = *(const float4*)(Qr + dc * 32);
      float4 f1 = *(const float4*)(Qr + dc * 32 + 4);
      half8 h;
      h[0] = (f16)f0.x; h[1] = (f16)f0.y; h[2] = (f16)f0.z; h[3] = (f16)f0.w;
      h[4] = (f16)f1.x; h[5] = (f16)f1.y; h[6] = (f16)f1.z; h[7] = (f16)f1.w;
      qf[dc] = h;
    }
  }

  // ones B-fragment: B[k][0] = 1 -> column 0 of an extra acc tile accumulates row-sum l
  const f16 ov = (col == 0) ? (f16)1.0f : (f16)0.0f;
  const half8 ones = {ov, ov, ov, ov, ov, ov, ov, ov};

  const floatx4 fzero = {0.f, 0.f, 0.f, 0.f};
  floatx4 o[32];                      // O: 16 rows x 512 cols, 32 n-tiles
  floatx4 ol = fzero;                 // l accumulator tile
#pragma unroll
  for (int nt = 0; nt < 32; ++nt) o[nt] = fzero;
  float m_i[4] = {-3.0e38f, -3.0e38f, -3.0e38f, -3.0e38f};

  int4 kreg[8], vreg[8];
  // ---- prologue: stage key-tile 0 into buf 0 ----
#pragma unroll
  for (int i = 0; i < 8; ++i) {
    int sid = tid + i * 256;
    kreg[i] = *(const int4*)(KhB + (size_t)(sid >> 6) * DDIM + (sid & 63) * 8);
  }
#pragma unroll
  for (int i = 0; i < 8; ++i) {
    int sid = tid + i * 256;
    vreg[i] = *(const int4*)(VtB + (size_t)(sid >> 2) * SLEN + (sid & 3) * 8);
  }
#pragma unroll
  for (int i = 0; i < 8; ++i) {
    int sid = tid + i * 256;
    *(int4*)&Kh_l[0][sid >> 6][(sid & 63) * 8] = kreg[i];
  }
#pragma unroll
  for (int i = 0; i < 8; ++i) {
    int sid = tid + i * 256;
    *(int4*)&Vt_l[0][sid >> 2][(sid & 3) * 8] = vreg[i];
  }
  __syncthreads();

  int buf = 0;
#pragma unroll 1
  for (int kt = 0; kt < 64; ++kt) {
    // ---- prefetch next tile (global -> regs); ds_writes happen after compute ----
    const int pk0 = (kt + 1) * 32;
    if (kt < 63) {
#pragma unroll
      for (int i = 0; i < 8; ++i) {
        int sid = tid + i * 256;
        kreg[i] = *(const int4*)(KhB + (size_t)(pk0 + (sid >> 6)) * DDIM + (sid & 63) * 8);
      }
#pragma unroll
      for (int i = 0; i < 8; ++i) {
        int sid = tid + i * 256;
        vreg[i] = *(const int4*)(VtB + (size_t)(sid >> 2) * SLEN + pk0 + (sid & 3) * 8);
      }
    }

    // ---- scores: S[q][key] for 32 keys (two 16x16 tiles), K-depth 512 ----
    floatx4 s0 = fzero, s1 = fzero;
#pragma unroll
    for (int dc = 0; dc < 16; ++dc) {
      half8 k0f = *(const half8*)&Kh_l[buf][col][dc * 32 + quad * 8];
      half8 k1f = *(const half8*)&Kh_l[buf][col + 16][dc * 32 + quad * 8];
      s0 = __builtin_amdgcn_mfma_f32_16x16x32_f16(qf[dc], k0f, s0, 0, 0, 0);
      s1 = __builtin_amdgcn_mfma_f32_16x16x32_f16(qf[dc], k1f, s1, 0, 0, 0);
    }

    // ---- online softmax: rows = quad*4+i, cols spread over quad's 16 lanes ----
    float al[4];
    int need = 0;
#pragma unroll
    for (int i = 0; i < 4; ++i) {
      float c = fmaxf(s0[i], s1[i]);
      c = fmaxf(c, __shfl_xor(c, 1));
      c = fmaxf(c, __shfl_xor(c, 2));
      c = fmaxf(c, __shfl_xor(c, 4));
      c = fmaxf(c, __shfl_xor(c, 8));
      float mn = fmaxf(m_i[i], c);
      al[i] = __expf(m_i[i] - mn);   // exp(0)==1 exactly when max unchanged
      m_i[i] = mn;
      need |= (al[i] != 1.0f);
    }
    if (__any(need)) {
#pragma unroll
      for (int nt = 0; nt < 32; ++nt) {
#pragma unroll
        for (int i = 0; i < 4; ++i) o[nt][i] *= al[i];
      }
#pragma unroll
      for (int i = 0; i < 4; ++i) ol[i] *= al[i];
    }

    // ---- P = exp(s - m) -> fp16, C-layout -> LDS ----
#pragma unroll
    for (int i = 0; i < 4; ++i) {
      float p0 = __expf(s0[i] - m_i[i]);
      float p1 = __expf(s1[i] - m_i[i]);
      P_l[wave][quad * 4 + i][col]      = (f16)p0;
      P_l[wave][quad * 4 + i][col + 16] = (f16)p1;
    }
    // A-layout read (same wave; compiler inserts lgkmcnt wait)
    half8 ap = *(const half8*)&P_l[wave][col][quad * 8];

    // ---- PV: O[q][d] += P(16x32) * V(32x512); B[k=key][n=d] from Vt_l[d][key] ----
#pragma unroll
    for (int nt = 0; nt < 32; ++nt) {
      half8 vf = *(const half8*)&Vt_l[buf][nt * 16 + col][quad * 8];
      o[nt] = __builtin_amdgcn_mfma_f32_16x16x32_f16(ap, vf, o[nt], 0, 0, 0);
    }
    ol = __builtin_amdgcn_mfma_f32_16x16x32_f16(ap, ones, ol, 0, 0, 0);

    // ---- write prefetched tile into back buffer (safe: its readers finished before
    //      the PREVIOUS barrier), then barrier, flip ----
    if (kt < 63) {
      const int nb = buf ^ 1;
#pragma unroll
      for (int i = 0; i < 8; ++i) {
        int sid = tid + i * 256;
        *(int4*)&Kh_l[nb][sid >> 6][(sid & 63) * 8] = kreg[i];
      }
#pragma unroll
      for (int i = 0; i < 8; ++i) {
        int sid = tid + i * 256;
        *(int4*)&Vt_l[nb][sid >> 2][(sid & 3) * 8] = vreg[i];
      }
    }
    __syncthreads();
    buf ^= 1;
  }

  // ---- epilogue: divide by l (col 0 of ol, lane quad*16) and store ----
  float* Ob = Out + (size_t)(b * SLEN + q0) * DDIM;
#pragma unroll
  for (int i = 0; i < 4; ++i) {
    float li = __shfl(ol[i], (quad << 4));
    float rl = 1.0f / li;
#pragma unroll
    for (int nt = 0; nt < 32; ++nt) {
      Ob[(size_t)(quad * 4 + i) * DDIM + nt * 16 + col] = o[nt][i] * rl;
    }
  }
}

extern "C" void kernel_launch(void* const* d_in, const int* in_sizes, int n_in,
                              void* d_out, int out_size, void* d_ws, size_t ws_size,
                              hipStream_t stream) {
  const float* Qp = (const float*)d_in[0];
  const float* Kp = (const float*)d_in[1];
  const float* Vp = (const float*)d_in[2];
  float* Op = (float*)d_out;

  // ws: Khg fp16 [8][2048][512] (16 MiB) | Vtg fp16 [8][512][2048] (16 MiB)
  f16* Khg = (f16*)d_ws;
  f16* Vtg = (f16*)((char*)d_ws + (size_t)BATCH * SLEN * DDIM * sizeof(f16));

  prep_kernel<<<dim3(8192 + 2048), dim3(256), 0, stream>>>(Kp, Vp, Khg, Vtg);
  attn_kernel<<<dim3(SLEN / 64, BATCH), dim3(256), 0, stream>>>(Qp, Khg, Vtg, Op);
}

// Round 2
// 505.954 us; speedup vs baseline: 1.3003x; 1.3003x over previous
//
#include <hip/hip_runtime.h>

#define BATCH 8
#define SLEN  2048
#define DDIM  512

typedef _Float16 f16;
typedef _Float16 half8  __attribute__((ext_vector_type(8)));
typedef _Float16 half4v __attribute__((ext_vector_type(4)));
typedef float    floatx4 __attribute__((ext_vector_type(4)));

// ---------------- pre-pass: K -> fp16 [B][S][D], V -> fp16 transposed [B][D][S] ----------------
__global__ __launch_bounds__(256) void prep_kernel(
    const float* __restrict__ Kin, const float* __restrict__ Vin,
    f16* __restrict__ Khg, f16* __restrict__ Vtg)
{
  __shared__ f16 vt[64][264];        // [d][s] tile, stride 264 (528B)
  const int tid = threadIdx.x;
  const int bid = blockIdx.x;
  if (bid < 8192) {
    // K convert: 8192 blocks * 256 threads * 1 float4
    const int i4 = bid * 256 + tid;
    float4 v = ((const float4*)Kin)[i4];
    half4v h;
    h.x = (f16)v.x; h.y = (f16)v.y; h.z = (f16)v.z; h.w = (f16)v.w;
    *(half4v*)(Khg + (size_t)i4 * 4) = h;
  } else {
    // V transpose: 512 blocks = 8 batches * 8 s-tiles(256) * 8 d-tiles(64)
    const int vb  = bid - 8192;
    const int b   = vb >> 6;
    const int rem = vb & 63;
    const int s0  = (rem >> 3) * 256;
    const int d0  = (rem & 7) * 64;
    const float* Vb = Vin + (size_t)b * SLEN * DDIM;
    const int d4 = (tid & 15) * 4;
    const int sb = (tid >> 4) * 4;
#pragma unroll
    for (int i = 0; i < 4; ++i) {
      const int ss = sb + i * 64;
      float fa[4][4];
#pragma unroll
      for (int j = 0; j < 4; ++j) {
        float4 f = *(const float4*)(Vb + (size_t)(s0 + ss + j) * DDIM + d0 + d4);
        fa[j][0] = f.x; fa[j][1] = f.y; fa[j][2] = f.z; fa[j][3] = f.w;
      }
#pragma unroll
      for (int k = 0; k < 4; ++k) {
        half4v hv;
        hv.x = (f16)fa[0][k]; hv.y = (f16)fa[1][k];
        hv.z = (f16)fa[2][k]; hv.w = (f16)fa[3][k];
        *(half4v*)&vt[d4 + k][ss] = hv;   // 8B write, 2-way banks
      }
    }
    __syncthreads();
    f16* VtB = Vtg + (size_t)b * DDIM * SLEN;
#pragma unroll
    for (int i = 0; i < 8; ++i) {
      const int c   = tid + i * 256;
      const int rd  = c >> 5;
      const int sseg = c & 31;
      *(int4*)(VtB + (size_t)(d0 + rd) * SLEN + s0 + sseg * 8) = *(const int4*)&vt[rd][sseg * 8];
    }
  }
}

// ---------------- flash attention main kernel ----------------
// grid (S/64, B), block 512 = 8 waves. wave = (h = wave>>2, pid = wave&3).
// pid picks 16 q-rows; h picks key-half (QK^T) and n-half (PV).
// Per-wave: qf[16] (full D), o[16] (16q x 256d), online softmax state for 16 rows.
__global__ __launch_bounds__(512, 2) void attn_kernel(
    const float* __restrict__ Q, const f16* __restrict__ Khg,
    const f16* __restrict__ Vtg, float* __restrict__ Out)
{
  // LDS: 66,560 + 81,920 + 5,120 + 512 = 154,112 B -> 1 block/CU, 8 waves
  __shared__ f16 Kh_l[2][32][520];   // [buf][key][d]   stride 1040B -> 2-way banks
  __shared__ f16 Vt_l[2][512][40];   // [buf][d][key]   stride 80B   -> 2-way banks
  __shared__ f16 P_l[4][16][40];     // per-pid P tile (16q x 32k)
  __shared__ float pmax[4][2][16];   // per-pid per-half row maxima

  const int tid  = threadIdx.x;
  const int lane = tid & 63;
  const int wave = tid >> 6;   // 0..7
  const int pid  = wave & 3;
  const int h    = wave >> 2;
  const int col  = lane & 15;
  const int quad = lane >> 4;
  const int b    = blockIdx.y;
  const int q0   = blockIdx.x * 64 + pid * 16;

  const f16* KhB = Khg + (size_t)b * SLEN * DDIM;
  const f16* VtB = Vtg + (size_t)b * DDIM * SLEN;

  // Q A-fragments (full D): A[m=col][k=quad*8+j], d = dc*32 + quad*8 + j
  half8 qf[16];
  {
    const float* Qr = Q + (size_t)(b * SLEN + q0 + col) * DDIM + quad * 8;
#pragma unroll
    for (int dc = 0; dc < 16; ++dc) {
      float4 f0 = *(const float4*)(Qr + dc * 32);
      float4 f1 = *(const float4*)(Qr + dc * 32 + 4);
      half8 hq;
      hq[0] = (f16)f0.x; hq[1] = (f16)f0.y; hq[2] = (f16)f0.z; hq[3] = (f16)f0.w;
      hq[4] = (f16)f1.x; hq[5] = (f16)f1.y; hq[6] = (f16)f1.z; hq[7] = (f16)f1.w;
      qf[dc] = hq;
    }
  }

  // ones B-fragment: col 0 of the l-accumulator tile collects row-sums
  const f16 ov = (col == 0) ? (f16)1.0f : (f16)0.0f;
  const half8 ones = {ov, ov, ov, ov, ov, ov, ov, ov};

  const floatx4 fzero = {0.f, 0.f, 0.f, 0.f};
  floatx4 o[16];                     // O: 16 rows x 256 cols (n-half h)
  floatx4 ol = fzero;
#pragma unroll
  for (int nt = 0; nt < 16; ++nt) o[nt] = fzero;
  float m_i[4] = {-3.0e38f, -3.0e38f, -3.0e38f, -3.0e38f};

  int4 kr[4], vr[4];
  // ---- prologue: stage key-tile 0 into buf 0 ----
#pragma unroll
  for (int i = 0; i < 4; ++i) {
    const int row = wave + i * 8;
    kr[i] = *(const int4*)(KhB + (size_t)row * DDIM + lane * 8);
  }
#pragma unroll
  for (int i = 0; i < 4; ++i) {
    const int c = tid + i * 512;
    vr[i] = *(const int4*)(VtB + (size_t)(c >> 2) * SLEN + (c & 3) * 8);
  }
#pragma unroll
  for (int i = 0; i < 4; ++i) {
    const int row = wave + i * 8;
    *(int4*)&Kh_l[0][row][lane * 8] = kr[i];
  }
#pragma unroll
  for (int i = 0; i < 4; ++i) {
    const int c = tid + i * 512;
    *(int4*)&Vt_l[0][c >> 2][(c & 3) * 8] = vr[i];
  }
  __syncthreads();

  int buf = 0;
#pragma unroll 1
  for (int kt = 0; kt < 64; ++kt) {
    // ---- global loads for next tile (consumed after barrier #1) ----
    if (kt < 63) {
      const int k0n = (kt + 1) * 32;
#pragma unroll
      for (int i = 0; i < 4; ++i) {
        const int row = wave + i * 8;
        kr[i] = *(const int4*)(KhB + (size_t)(k0n + row) * DDIM + lane * 8);
      }
#pragma unroll
      for (int i = 0; i < 4; ++i) {
        const int c = tid + i * 512;
        vr[i] = *(const int4*)(VtB + (size_t)(c >> 2) * SLEN + k0n + (c & 3) * 8);
      }
    }

    // ---- QK^T: this wave's 16 keys (kbase = h*16), full D ----
    floatx4 s = fzero;
#pragma unroll
    for (int dc = 0; dc < 16; ++dc) {
      half8 kf = *(const half8*)&Kh_l[buf][h * 16 + col][dc * 32 + quad * 8];
      s = __builtin_amdgcn_mfma_f32_16x16x32_f16(qf[dc], kf, s, 0, 0, 0);
    }

    // ---- partial row-max over this wave's 16 keys ----
    float c4[4];
#pragma unroll
    for (int i = 0; i < 4; ++i) {
      float c = s[i];
      c = fmaxf(c, __shfl_xor(c, 1));
      c = fmaxf(c, __shfl_xor(c, 2));
      c = fmaxf(c, __shfl_xor(c, 4));
      c = fmaxf(c, __shfl_xor(c, 8));
      c4[i] = c;
    }
    if (col == 0) {
#pragma unroll
      for (int i = 0; i < 4; ++i) pmax[pid][h][quad * 4 + i] = c4[i];
    }
    __syncthreads();   // #1: pmax visible (also drains global loads)

    // ---- combine maxima, rescale, compute P ----
    float al[4];
    int need = 0;
#pragma unroll
    for (int i = 0; i < 4; ++i) {
      float m2 = fmaxf(pmax[pid][0][quad * 4 + i], pmax[pid][1][quad * 4 + i]);
      float mn = fmaxf(m_i[i], m2);
      al[i] = __expf(m_i[i] - mn);   // ==1 exactly when max unchanged
      m_i[i] = mn;
      need |= (al[i] != 1.0f);
    }
    if (__any(need)) {
#pragma unroll
      for (int nt = 0; nt < 16; ++nt) {
#pragma unroll
        for (int i = 0; i < 4; ++i) o[nt][i] *= al[i];
      }
#pragma unroll
      for (int i = 0; i < 4; ++i) ol[i] *= al[i];
    }
#pragma unroll
    for (int i = 0; i < 4; ++i) {
      float p = __expf(s[i] - m_i[i]);
      P_l[pid][quad * 4 + i][h * 16 + col] = (f16)p;
    }

    // ---- stage next tile into back buffer (safe: nb's last readers finished
    //      before THIS iteration's barrier #1; next readers wait on #2) ----
    if (kt < 63) {
      const int nb = buf ^ 1;
#pragma unroll
      for (int i = 0; i < 4; ++i) {
        const int row = wave + i * 8;
        *(int4*)&Kh_l[nb][row][lane * 8] = kr[i];
      }
#pragma unroll
      for (int i = 0; i < 4; ++i) {
        const int c = tid + i * 512;
        *(int4*)&Vt_l[nb][c >> 2][(c & 3) * 8] = vr[i];
      }
    }
    __syncthreads();   // #2: P + staged tile visible

    // ---- PV: O[16q][n-half] += P(16x32) * V(32x256) ----
    half8 ap = *(const half8*)&P_l[pid][col][quad * 8];
#pragma unroll
    for (int nt = 0; nt < 16; ++nt) {
      half8 vf = *(const half8*)&Vt_l[buf][h * 256 + nt * 16 + col][quad * 8];
      o[nt] = __builtin_amdgcn_mfma_f32_16x16x32_f16(ap, vf, o[nt], 0, 0, 0);
    }
    ol = __builtin_amdgcn_mfma_f32_16x16x32_f16(ap, ones, ol, 0, 0, 0);

    buf ^= 1;
  }

  // ---- epilogue: divide by l and store this wave's n-half ----
  float* Ob = Out + (size_t)(b * SLEN + q0) * DDIM;
#pragma unroll
  for (int i = 0; i < 4; ++i) {
    float li = __shfl(ol[i], (quad << 4));   // col 0 of l tile
    float rl = 1.0f / li;
#pragma unroll
    for (int nt = 0; nt < 16; ++nt) {
      Ob[(size_t)(quad * 4 + i) * DDIM + h * 256 + nt * 16 + col] = o[nt][i] * rl;
    }
  }
}

extern "C" void kernel_launch(void* const* d_in, const int* in_sizes, int n_in,
                              void* d_out, int out_size, void* d_ws, size_t ws_size,
                              hipStream_t stream) {
  const float* Qp = (const float*)d_in[0];
  const float* Kp = (const float*)d_in[1];
  const float* Vp = (const float*)d_in[2];
  float* Op = (float*)d_out;

  // ws: Khg fp16 [8][2048][512] (16 MiB) | Vtg fp16 [8][512][2048] (16 MiB)
  f16* Khg = (f16*)d_ws;
  f16* Vtg = (f16*)((char*)d_ws + (size_t)BATCH * SLEN * DDIM * sizeof(f16));

  prep_kernel<<<dim3(8192 + 512), dim3(256), 0, stream>>>(Kp, Vp, Khg, Vtg);
  attn_kernel<<<dim3(SLEN / 64, BATCH), dim3(512), 0, stream>>>(Qp, Khg, Vtg, Op);
}